// Round 8
// baseline (495.031 us; speedup 1.0000x reference)
//
#include <hip/hip_runtime.h>
#include <cstdint>
#include <cstddef>

typedef _Float16 f16;
typedef _Float16 f16x8 __attribute__((ext_vector_type(8)));
typedef float f32x4 __attribute__((ext_vector_type(4)));

// ---------------- helpers ----------------

__device__ __forceinline__ void gload16(const void* g, void* l) {
  // async global->LDS, 16B per lane; LDS dest must be wave-uniform base + lane*16
  __builtin_amdgcn_global_load_lds((const __attribute__((address_space(1))) void*)g,
                                   (__attribute__((address_space(3))) void*)l, 16, 0, 0);
}

__device__ __forceinline__ uint32_t packh2(float a, float b) {
  f16 ha = (f16)a, hb = (f16)b;
  uint16_t ua = __builtin_bit_cast(uint16_t, ha);
  uint16_t ub = __builtin_bit_cast(uint16_t, hb);
  return (uint32_t)ua | ((uint32_t)ub << 16);
}

// ---------------- prep ----------------
// lut layout: kt-tiled [kt][o][64] with (a) k-order permutation chunk16 =
// half*4 + c_local (matches the attn kernel's store order) and (b) the GEMM
// LDS XOR swizzle baked per row: within-row 16B-chunk stored at
// (chunk16 ^ (o&7)). GEMM then stages B with a fully LINEAR 16KB copy and
// reads fragments with the standard co XOR -> conflict-free (R0-verified).
// cn[c*16+k] = ||cent[c,k]||^2.
__global__ __launch_bounds__(256) void prep_kernel(
    const float* __restrict__ cent1, const float* __restrict__ wsub1,
    const float* __restrict__ cent2, const float* __restrict__ wsub2,
    const float* __restrict__ g1, const float* __restrict__ be1,
    const float* __restrict__ mu1, const float* __restrict__ va1,
    const float* __restrict__ g2, const float* __restrict__ be2,
    const float* __restrict__ mu2, const float* __restrict__ va2,
    f16* __restrict__ lut1, f16* __restrict__ lut2,
    float* __restrict__ cn1, float* __restrict__ cn2,
    float* __restrict__ bn1i, float* __restrict__ bn1a,
    float* __restrict__ bn2i, float* __restrict__ bn2a,
    float* __restrict__ pool)
{
  int bx = blockIdx.x, t = threadIdx.x;
  if (bx < 8192) {
    int conv = bx >> 12, ck = bx & 4095;
    int cg = ck >> 4, cw = ck & 15;               // channel, codeword
    const float* cent = conv ? cent2 : cent1;
    const float* wsub = conv ? wsub2 : wsub1;
    f16* lut = conv ? lut2 : lut1;
    float s = 0.f;
#pragma unroll
    for (int sv = 0; sv < 9; ++sv)
      s += cent[ck*9 + sv] * wsub[(cg*9 + sv)*256 + t];
    int kt = cg >> 2, cl = cg & 3, half = cw >> 3, j = cw & 7;
    int chunk = (half*4 + cl) ^ (t & 7);          // permuted + row-XOR
    lut[(size_t)kt*16384 + (size_t)t*64 + chunk*8 + j] = (f16)s;
  } else {
    for (int j = 0; j < 16; ++j) {
      int ck = j*256 + t;
      float s1 = 0.f, s2 = 0.f;
#pragma unroll
      for (int sv = 0; sv < 9; ++sv) {
        float a = cent1[ck*9 + sv]; s1 += a*a;
        float b = cent2[ck*9 + sv]; s2 += b*b;
      }
      cn1[ck] = s1; cn2[ck] = s2;
      pool[ck] = 0.f;                 // ws is re-poisoned 0xAA every launch
    }
    float i1 = g1[t] * rsqrtf(va1[t] + 1e-5f);
    bn1i[t] = i1; bn1a[t] = be1[t] - mu1[t]*i1;
    float i2 = g2[t] * rsqrtf(va2[t] + 1e-5f);
    bn2i[t] = i2; bn2a[t] = be2[t] - mu2[t]*i2;
  }
}

// ---------------- attention (soft codeword assignment) ----------------
// Thread = one (position, channel): grid (196, 64); block = 64 positions x
// the 4 channels of K-chunk kt = blockIdx.y. Output layout [kt][n][64] fp16
// with the GEMM A-tile XOR swizzle baked in: thread (n, cl) stores its two
// 16B chunks at ((0+cl)^ (n&7)) and ((4+cl)^(n&7)). Lanes 0-3 share n, so
// each store instruction covers exactly one full 64B line (the XOR only
// permutes lanes within the line) -> fully coalesced, no LDS, no conflicts.
// 12544 tiny blocks -> ~12 blocks/CU of TLP to hide the patch-load latency
// (vs R0's LDS-bounce write phase: 2.4M bank conflicts, 2.1 TB/s).
// SRC==0: src is x, NCHW [16][256][28][28]. SRC==1: src is y1, NHWC [12544][256].
template<int SRC>
__global__ __launch_bounds__(256) void attn_kernel(
    const float* __restrict__ src, const float* __restrict__ cent,
    const float* __restrict__ cn, f16* __restrict__ attn)
{
  int t = threadIdx.x;
  int nl = t >> 2, cl = t & 3;
  int kt = blockIdx.y;
  int c = kt*4 + cl;
  int P = blockIdx.x*64 + nl;
  int b = P / 784, n = P % 784, h = n / 28, w = n % 28;
  const float* pb = (SRC == 0) ? src + ((size_t)b*256 + c)*784
                               : src + (size_t)b*200704 + c;
  float p[9];
#pragma unroll
  for (int dh = 0; dh < 3; ++dh)
#pragma unroll
    for (int dw = 0; dw < 3; ++dw) {
      int hh = h + dh - 1, ww = w + dw - 1;
      bool ok = (hh >= 0) && (hh < 28) && (ww >= 0) && (ww < 28);
      int o = ok ? (hh*28 + ww) : 0;
      p[dh*3+dw] = ok ? pb[(SRC == 0) ? o : o*256] : 0.f;
    }
  const float* ce = cent + (size_t)c*144;   // [16][9], L1-resident
  const float* cq = cn + c*16;
  float e[16];
#pragma unroll
  for (int k = 0; k < 16; ++k) {
    float d = 0.f;
#pragma unroll
    for (int s = 0; s < 9; ++s) d += p[s]*ce[k*9 + s];
    e[k] = 2.f*d - cq[k];                   // ||p||^2 cancels in softmax
  }
  float mx = e[0];
#pragma unroll
  for (int k = 1; k < 16; ++k) mx = fmaxf(mx, e[k]);
  float sum = 0.f;
#pragma unroll
  for (int k = 0; k < 16; ++k) { e[k] = __expf(e[k] - mx); sum += e[k]; }
  float rs = 1.f / sum;
  uint4 q0 = make_uint4(packh2(e[0]*rs,  e[1]*rs),  packh2(e[2]*rs,  e[3]*rs),
                        packh2(e[4]*rs,  e[5]*rs),  packh2(e[6]*rs,  e[7]*rs));
  uint4 q1 = make_uint4(packh2(e[8]*rs,  e[9]*rs),  packh2(e[10]*rs, e[11]*rs),
                        packh2(e[12]*rs, e[13]*rs), packh2(e[14]*rs, e[15]*rs));
  f16* dst = attn + ((size_t)kt*12544 + P)*64;
  int r7 = P & 7;                           // == LDS-tile row&7 (row0 %128==0)
  *(uint4*)(dst + ((0 + cl) ^ r7)*8) = q0;  // logical chunk cl   (cw 0..7)
  *(uint4*)(dst + ((4 + cl) ^ r7)*8) = q1;  // logical chunk 4+cl (cw 8..15)
}

// ---------------- GEMM: C[12544,256] = A[kt][12544][64] x B[kt][256][64], fused BN (+ReLU) --
// R0's verified 128x128xBK64 structure (4 waves as 2x2, 64x64 wave tile,
// full-K, LDS double buffer, one-phase-ahead global_load_lds staging). Both
// operands are kt-tiled with the row XOR pre-baked -> staging is a LINEAR
// contiguous 16KB copy per tile (no source swizzle math). Fragment reads use
// the standard co XOR (conflict-free, 0 conflicts measured in R0/R4).
template<bool RELU>
__global__ __launch_bounds__(256, 2) void gemm_kernel(
    const f16* __restrict__ A, const f16* __restrict__ B,
    const float* __restrict__ inv, const float* __restrict__ add,
    float* __restrict__ Cout)
{
  __shared__ __align__(16) f16 smem[4*8192];    // buf0:{A,B} buf1:{A,B}, 16KB each
  f16* As0 = smem;
  f16* Bs0 = smem + 8192;
  f16* As1 = smem + 16384;
  f16* Bs1 = smem + 24576;

  // grid 208 = 16 x 13; xcd = bx&7 stable within a (mt, nt) pair
  int bx = blockIdx.x;
  int xw = bx & 7, nt = (bx >> 3) & 1, g = bx >> 4;
  int mt = xw + 8*g;
  if (mt >= 98) return;
  int row0 = mt*128, col0 = nt*128;

  int t = threadIdx.x;
  int lane = t & 63, wave = t >> 6;
  int wm = wave >> 1, wn = wave & 1;  // 2x2 wave grid, wave tile 64x64
  int fm = lane & 15, fq = lane >> 4;

  const f16* Ag = A + (size_t)row0*64 + t*8;    // + ktc*802816 per stage
  const f16* Bg = B + (size_t)col0*64 + t*8;    // + ktc*16384 per stage

  f32x4 acc[4][4] = {};

  auto stage = [&](f16* Ab, f16* Bb, int ktc) { // linear 16KB copies
    const f16* as = Ag + (size_t)ktc*802816;    // 12544*64
    const f16* bs = Bg + (size_t)ktc*16384;
#pragma unroll
    for (int ii = 0; ii < 4; ++ii) {
      gload16(as + ii*2048, Ab + t*8 + ii*2048);
      gload16(bs + ii*2048, Bb + t*8 + ii*2048);
    }
  };
  auto compute = [&](const f16* Ab, const f16* Bb) {
#pragma unroll
    for (int ks = 0; ks < 2; ++ks) {
      int co = ((ks*4 + fq) ^ (fm & 7)) * 8;
      f16x8 af[4], bf[4];
#pragma unroll
      for (int m2 = 0; m2 < 4; ++m2)
        af[m2] = *(const f16x8*)(Ab + (wm*64 + m2*16 + fm)*64 + co);
#pragma unroll
      for (int n2 = 0; n2 < 4; ++n2)
        bf[n2] = *(const f16x8*)(Bb + (wn*64 + n2*16 + fm)*64 + co);
#pragma unroll
      for (int m2 = 0; m2 < 4; ++m2)
#pragma unroll
        for (int n2 = 0; n2 < 4; ++n2)
          acc[m2][n2] = __builtin_amdgcn_mfma_f32_16x16x32_f16(af[m2], bf[n2], acc[m2][n2], 0, 0, 0);
    }
  };

  stage(As0, Bs0, 0);                  // prologue: tile 0
#pragma unroll 1
  for (int kt2 = 0; kt2 < 32; ++kt2) {
    __syncthreads();                   // tile 2k landed; buf1 free
    stage(As1, Bs1, 2*kt2 + 1);        // prefetch tile 2k+1
    compute(As0, Bs0);                 // compute tile 2k
    __syncthreads();                   // tile 2k+1 landed; buf0 free
    if (kt2 < 31) stage(As0, Bs0, 2*kt2 + 2);
    compute(As1, Bs1);                 // compute tile 2k+1
  }

  // epilogue: direct write (full-K per wave); C/D: col=lane&15, row=fq*4+r
#pragma unroll
  for (int n2 = 0; n2 < 4; ++n2) {
    int colg = col0 + wn*64 + n2*16 + fm;
    float iv = inv[colg], ad = add[colg];
#pragma unroll
    for (int m2 = 0; m2 < 4; ++m2) {
      int rowg = row0 + wm*64 + m2*16 + fq*4;
#pragma unroll
      for (int r = 0; r < 4; ++r) {
        float v = acc[m2][n2][r]*iv + ad;
        if (RELU) v = fmaxf(v, 0.f);
        Cout[(size_t)(rowg + r)*256 + colg] = v;
      }
    }
  }
}

// ---------------- global average pool (partial sums, atomics) ----------------
__global__ __launch_bounds__(256) void pool_kernel(const float* __restrict__ y2,
                                                   float* __restrict__ pool)
{
  int b = blockIdx.x, t = threadIdx.x;
  int r0 = blockIdx.y * 112;
  float s = 0.f;
  for (int r = 0; r < 112; ++r)
    s += y2[((size_t)b*784 + r0 + r)*256 + t];
  atomicAdd(&pool[b*256 + t], s);
}

// ---------------- SE MLP: scale = sigmoid(relu(mean @ w1 + b1) @ w2 + b2) ----------------
__global__ __launch_bounds__(256) void se_kernel(
    const float* __restrict__ pool, const float* __restrict__ w1, const float* __restrict__ b1,
    const float* __restrict__ w2, const float* __restrict__ b2, float* __restrict__ scale)
{
  __shared__ float m[256];
  __shared__ float hbuf[16];
  int b = blockIdx.x, t = threadIdx.x;
  m[t] = pool[b*256 + t] * (1.f/784.f);
  __syncthreads();
  if (t < 16) {
    float a = b1[t];
    for (int o = 0; o < 256; ++o) a += m[o]*w1[o*16 + t];
    hbuf[t] = fmaxf(a, 0.f);
  }
  __syncthreads();
  float a = b2[t];
#pragma unroll
  for (int jj = 0; jj < 16; ++jj) a += hbuf[jj]*w2[jj*256 + t];
  scale[b*256 + t] = 1.f/(1.f + __expf(-a));
}

// ---------------- final: out = relu(y2 * scale + x), NCHW ----------------
__global__ __launch_bounds__(256) void final_kernel(
    const float* __restrict__ y2, const float* __restrict__ scale,
    const float* __restrict__ x, float* __restrict__ out)
{
  int idx = blockIdx.x*256 + threadIdx.x;
  int b = idx / 200704, rem = idx % 200704;
  int o = rem / 784, hw = rem % 784;
  float v = y2[((size_t)b*784 + hw)*256 + o]*scale[b*256 + o] + x[idx];
  out[idx] = fmaxf(v, 0.f);
}

// ---------------- launch ----------------
extern "C" void kernel_launch(void* const* d_in, const int* in_sizes, int n_in,
                              void* d_out, int out_size, void* d_ws, size_t ws_size,
                              hipStream_t stream) {
  const float* x     = (const float*)d_in[0];
  const float* cent1 = (const float*)d_in[1];
  const float* wsub1 = (const float*)d_in[2];
  const float* g1    = (const float*)d_in[3];
  const float* be1   = (const float*)d_in[4];
  const float* mu1   = (const float*)d_in[5];
  const float* va1   = (const float*)d_in[6];
  const float* cent2 = (const float*)d_in[7];
  const float* wsub2 = (const float*)d_in[8];
  const float* g2    = (const float*)d_in[9];
  const float* be2   = (const float*)d_in[10];
  const float* mu2   = (const float*)d_in[11];
  const float* va2   = (const float*)d_in[12];
  const float* sw1   = (const float*)d_in[13];
  const float* sb1   = (const float*)d_in[14];
  const float* sw2   = (const float*)d_in[15];
  const float* sb2   = (const float*)d_in[16];
  float* out = (float*)d_out;

  char* ws = (char*)d_ws;
  f16*   attn  = (f16*)(ws + 0);                  // [64][12544][64] = 102,760,448
  f16*   lut1  = (f16*)(ws + 102760448);          // 2 MB (kt-tiled + swizzled)
  f16*   lut2  = (f16*)(ws + 104857600);          // 2 MB
  float* y1    = (float*)(ws + 106954752);        // 12,845,056
  float* y2    = (float*)(ws + 119799808);        // 12,845,056
  float* cn1   = (float*)(ws + 132644864);        // 16 KB
  float* cn2   = (float*)(ws + 132661248);        // 16 KB
  float* bn1i  = (float*)(ws + 132677632);
  float* bn1a  = (float*)(ws + 132678656);
  float* bn2i  = (float*)(ws + 132679680);
  float* bn2a  = (float*)(ws + 132680704);
  float* pool  = (float*)(ws + 132681728);        // 16 KB
  float* scale = (float*)(ws + 132698112);        // 16 KB  (end ~126.6 MiB)

  prep_kernel<<<8193, 256, 0, stream>>>(cent1, wsub1, cent2, wsub2,
                                        g1, be1, mu1, va1, g2, be2, mu2, va2,
                                        lut1, lut2, cn1, cn2,
                                        bn1i, bn1a, bn2i, bn2a, pool);
  attn_kernel<0><<<dim3(196, 64), 256, 0, stream>>>(x, cent1, cn1, attn);
  gemm_kernel<true ><<<208, 256, 0, stream>>>(attn, lut1, bn1i, bn1a, y1);
  attn_kernel<1><<<dim3(196, 64), 256, 0, stream>>>(y1, cent2, cn2, attn);
  gemm_kernel<false><<<208, 256, 0, stream>>>(attn, lut2, bn2i, bn2a, y2);
  pool_kernel<<<dim3(16, 7), 256, 0, stream>>>(y2, pool);
  se_kernel<<<16, 256, 0, stream>>>(pool, sw1, sb1, sw2, sb2, scale);
  final_kernel<<<12544, 256, 0, stream>>>(y2, scale, x, out);
}

// Round 9
// 339.559 us; speedup vs baseline: 1.4579x; 1.4579x over previous
//
#include <hip/hip_runtime.h>
#include <cstdint>
#include <cstddef>

typedef _Float16 f16;
typedef _Float16 f16x8 __attribute__((ext_vector_type(8)));
typedef float f32x4 __attribute__((ext_vector_type(4)));
typedef float f32x2 __attribute__((ext_vector_type(2)));

// ---------------- helpers ----------------

__device__ __forceinline__ void gload16(const void* g, void* l) {
  // async global->LDS, 16B per lane; LDS dest must be wave-uniform base + lane*16
  __builtin_amdgcn_global_load_lds((const __attribute__((address_space(1))) void*)g,
                                   (__attribute__((address_space(3))) void*)l, 16, 0, 0);
}

__device__ __forceinline__ uint32_t packh2(float a, float b) {
  f16 ha = (f16)a, hb = (f16)b;
  uint16_t ua = __builtin_bit_cast(uint16_t, ha);
  uint16_t ub = __builtin_bit_cast(uint16_t, hb);
  return (uint32_t)ua | ((uint32_t)ub << 16);
}

// ---------------- prep ----------------
// lut layout: kt-tiled [kt][o][64]; k within chunk mapped as chunk16 = cl*2+half
// (cl = channel&3, half = cw>>3, j = cw&7), stored at phys chunk16^(o&7)
// (GEMM LDS XOR pre-baked -> linear B staging + conflict-free fragment reads).
// centP[c][j][s][2]: pair-interleaved centroids pre-scaled by 2 (j = cw pair,
// s = subvec elem) -> enables f32x2 packed-FMA dots with block-uniform
// (scalar-load) addresses in attn. cnP[c][j][2]: matching ||cent||^2 pairs.
__global__ __launch_bounds__(256) void prep_kernel(
    const float* __restrict__ cent1, const float* __restrict__ wsub1,
    const float* __restrict__ cent2, const float* __restrict__ wsub2,
    const float* __restrict__ g1, const float* __restrict__ be1,
    const float* __restrict__ mu1, const float* __restrict__ va1,
    const float* __restrict__ g2, const float* __restrict__ be2,
    const float* __restrict__ mu2, const float* __restrict__ va2,
    f16* __restrict__ lut1, f16* __restrict__ lut2,
    float* __restrict__ centP1, float* __restrict__ centP2,
    float* __restrict__ cnP1, float* __restrict__ cnP2,
    float* __restrict__ bn1i, float* __restrict__ bn1a,
    float* __restrict__ bn2i, float* __restrict__ bn2a,
    float* __restrict__ pool)
{
  int bx = blockIdx.x, t = threadIdx.x;
  if (bx < 8192) {
    int conv = bx >> 12, ck = bx & 4095;
    int cg = ck >> 4, cw = ck & 15;               // channel, codeword
    const float* cent = conv ? cent2 : cent1;
    const float* wsub = conv ? wsub2 : wsub1;
    f16* lut = conv ? lut2 : lut1;
    float s = 0.f;
#pragma unroll
    for (int sv = 0; sv < 9; ++sv)
      s += cent[ck*9 + sv] * wsub[(cg*9 + sv)*256 + t];
    int kt = cg >> 2, cl = cg & 3, half = cw >> 3, j = cw & 7;
    int chunk = (cl*2 + half) ^ (t & 7);          // chunk16 conv + row-XOR
    lut[(size_t)kt*16384 + (size_t)t*64 + chunk*8 + j] = (f16)s;
  } else if (bx < 8224) {
    int idx = bx - 8192;                          // 32 blocks: centP/cnP
    int conv = idx >> 4, cblk = idx & 15;
    const float* cent = conv ? cent2 : cent1;
    float* centP = conv ? centP2 : centP1;
    float* cnP   = conv ? cnP2 : cnP1;
    int c = cblk*16 + (t >> 4);
    int sub = t & 15, j = sub >> 1, e = sub & 1;
    int k = 2*j + e;
    const float* cs = cent + (size_t)(c*16 + k)*9;
    float ss = 0.f;
#pragma unroll
    for (int s = 0; s < 9; ++s) {
      float v = cs[s];
      centP[(size_t)c*144 + j*18 + s*2 + e] = 2.f*v;
      ss += v*v;
    }
    cnP[c*16 + j*2 + e] = ss;
  } else {
    for (int j = 0; j < 16; ++j)
      pool[j*256 + t] = 0.f;                      // ws re-poisoned every launch
    float i1 = g1[t] * rsqrtf(va1[t] + 1e-5f);
    bn1i[t] = i1; bn1a[t] = be1[t] - mu1[t]*i1;
    float i2 = g2[t] * rsqrtf(va2[t] + 1e-5f);
    bn2i[t] = i2; bn2a[t] = be2[t] - mu2[t]*i2;
  }
}

// ---------------- attention (soft codeword assignment) ----------------
// R0's proven structure (52us @ VALUBusy 55%): block = 256 positions x ONE
// channel-pair c0 = 2*blockIdx.y -> centroid/cn addresses are BLOCK-UNIFORM
// => scalar s_load broadcasts, zero per-lane VMEM for centroids (R8's 142us
// regression was per-lane channel -> 40 VMEM loads/thread of broadcast data).
// Dots via f32x2 packed-FMA on pair-interleaved centP. sbuf LDS bounce
// (write [j][t]: conflict-free; read 4-lane gather: R0-verified). Store phase
// emits the kt-tiled GEMM layout [kt][P][64] with chunk16 = cl*2+half ^ (P&7);
// the 4 lanes of a segment write chunks {4a..4a+3}^r7 = one COMPLETE 64B line
// (XOR maps 4-aligned blocks to 4-aligned blocks) -> full-line coalescing.
// SRC==0: src is x, NCHW [16][256][28][28]. SRC==1: src is y1, NHWC [12544][256].
template<int SRC>
__global__ __launch_bounds__(256) void attn_kernel(
    const float* __restrict__ src, const float* __restrict__ centP,
    const float* __restrict__ cnP, f16* __restrict__ attn)
{
  __shared__ uint32_t sbuf[16*256];   // [j=cc*8+pair][t]
  int t = threadIdx.x;
  int P = blockIdx.x*256 + t;         // 0..12543
  int b = P / 784, n = P % 784, h = n / 28, w = n % 28;
  int by = blockIdx.y;                // channel pair 0..127
  int c0 = by*2;
  int kt = by >> 1, cl0 = (by & 1)*2;
  int offc[9]; float msk[9];
#pragma unroll
  for (int dh = 0; dh < 3; ++dh)
#pragma unroll
    for (int dw = 0; dw < 3; ++dw) {
      int hh = h + dh - 1, ww = w + dw - 1;
      bool ok = (hh >= 0) && (hh < 28) && (ww >= 0) && (ww < 28);
      offc[dh*3+dw] = ok ? (hh*28 + ww) : 0;
      msk[dh*3+dw] = ok ? 1.f : 0.f;
    }
  float p2[2][9];
  if (SRC == 1) {
#pragma unroll
    for (int s = 0; s < 9; ++s) {
      float2 v = *(const float2*)(src + ((size_t)b*784 + offc[s])*256 + c0);
      p2[0][s] = v.x * msk[s];
      p2[1][s] = v.y * msk[s];
    }
  }
#pragma unroll
  for (int cc = 0; cc < 2; ++cc) {
    int c = c0 + cc;
    float p[9];
#pragma unroll
    for (int s = 0; s < 9; ++s) {
      if (SRC == 0) p[s] = src[(size_t)(b*256 + c)*784 + offc[s]] * msk[s];
      else          p[s] = p2[cc][s];
    }
    const float* cp = centP + (size_t)c*144;   // block-uniform -> scalar loads
    const float* cq = cnP + c*16;
    f32x2 e2[8];
#pragma unroll
    for (int j = 0; j < 8; ++j) e2[j] = -*(const f32x2*)(cq + j*2);
#pragma unroll
    for (int s = 0; s < 9; ++s)
#pragma unroll
      for (int j = 0; j < 8; ++j)
        e2[j] += p[s] * (*(const f32x2*)(cp + j*18 + s*2));  // cent pre-x2
    float e[16];
#pragma unroll
    for (int j = 0; j < 8; ++j) { e[2*j] = e2[j][0]; e[2*j+1] = e2[j][1]; }
    float mx = e[0];
#pragma unroll
    for (int k = 1; k < 16; ++k) mx = fmaxf(mx, e[k]);
    float sum = 0.f;
#pragma unroll
    for (int k = 0; k < 16; ++k) { e[k] = __expf(e[k] - mx); sum += e[k]; }
    float r = 1.f / sum;
#pragma unroll
    for (int j = 0; j < 8; ++j)
      sbuf[(cc*8 + j)*256 + t] = packh2(e[2*j]*r, e[2*j+1]*r);
  }
  __syncthreads();
  // write phase: lane seg holds all 8 cw of (channel cc=seg>>1, half=seg&1)
  // for position r -> one 16B chunk; 4 segs -> one complete 64B line.
  int seg = t & 3;
#pragma unroll
  for (int i = 0; i < 4; ++i) {
    int r = i*64 + (t >> 2);
    uint4 v = make_uint4(sbuf[(seg*4+0)*256 + r], sbuf[(seg*4+1)*256 + r],
                         sbuf[(seg*4+2)*256 + r], sbuf[(seg*4+3)*256 + r]);
    int cl = cl0 + (seg >> 1), half = seg & 1;
    int chunk = (cl*2 + half) ^ (r & 7);
    *(uint4*)(attn + ((size_t)kt*12544 + blockIdx.x*256 + r)*64 + chunk*8) = v;
  }
}

// ---------------- GEMM: C[12544,256] = A[kt][12544][64] x B[kt][256][64], fused BN (+ReLU) --
// BM=128, BN=64 -> grid 392 (98x4, no dead blocks), LDS 48KB => 2 blocks/CU:
// 8 waves in 2 INDEPENDENT barrier groups (R8's 196-block version had one
// 4-wave group per CU -> lockstep latency exposure, ~80us). 4 waves as 2x2,
// wave tile 64x32, full-K, double-buffered one-phase-ahead global_load_lds
// staging; both operands kt-tiled with row-XOR pre-baked -> linear copies.
template<bool RELU>
__global__ __launch_bounds__(256, 2) void gemm_kernel(
    const f16* __restrict__ A, const f16* __restrict__ B,
    const float* __restrict__ inv, const float* __restrict__ add,
    float* __restrict__ Cout)
{
  __shared__ __align__(16) f16 smem[2*12288];   // buf: A 16KB + B 8KB; x2
  f16* As0 = smem;
  f16* Bs0 = smem + 8192;
  f16* As1 = smem + 12288;
  f16* Bs1 = smem + 20480;

  int bx = blockIdx.x;
  int mt = bx >> 2, nt = bx & 3;
  int row0 = mt*128, col0 = nt*64;

  int t = threadIdx.x;
  int lane = t & 63, wave = t >> 6;
  int wm = wave >> 1, wn = wave & 1;  // 2x2 wave grid, wave tile 64x32
  int fm = lane & 15, fq = lane >> 4;

  const f16* Ag = A + (size_t)row0*64 + t*8;    // + ktc*802816 per stage
  const f16* Bg = B + (size_t)col0*64 + t*8;    // + ktc*16384 per stage

  f32x4 acc[4][2] = {};

  auto stage = [&](f16* Ab, f16* Bb, int ktc) { // linear contiguous copies
    const f16* as = Ag + (size_t)ktc*802816;    // 12544*64
    const f16* bs = Bg + (size_t)ktc*16384;
#pragma unroll
    for (int ii = 0; ii < 4; ++ii)
      gload16(as + ii*2048, Ab + t*8 + ii*2048);
#pragma unroll
    for (int ii = 0; ii < 2; ++ii)
      gload16(bs + ii*2048, Bb + t*8 + ii*2048);
  };
  auto compute = [&](const f16* Ab, const f16* Bb) {
#pragma unroll
    for (int ks = 0; ks < 2; ++ks) {
      int co = ((ks*4 + fq) ^ (fm & 7)) * 8;
      f16x8 af[4], bf[2];
#pragma unroll
      for (int m2 = 0; m2 < 4; ++m2)
        af[m2] = *(const f16x8*)(Ab + (wm*64 + m2*16 + fm)*64 + co);
#pragma unroll
      for (int n2 = 0; n2 < 2; ++n2)
        bf[n2] = *(const f16x8*)(Bb + (wn*32 + n2*16 + fm)*64 + co);
#pragma unroll
      for (int m2 = 0; m2 < 4; ++m2)
#pragma unroll
        for (int n2 = 0; n2 < 2; ++n2)
          acc[m2][n2] = __builtin_amdgcn_mfma_f32_16x16x32_f16(af[m2], bf[n2], acc[m2][n2], 0, 0, 0);
    }
  };

  stage(As0, Bs0, 0);                  // prologue: tile 0
#pragma unroll 1
  for (int kt2 = 0; kt2 < 32; ++kt2) {
    __syncthreads();                   // tile 2k landed; buf1 free
    stage(As1, Bs1, 2*kt2 + 1);        // prefetch tile 2k+1
    compute(As0, Bs0);                 // compute tile 2k
    __syncthreads();                   // tile 2k+1 landed; buf0 free
    if (kt2 < 31) stage(As0, Bs0, 2*kt2 + 2);
    compute(As1, Bs1);                 // compute tile 2k+1
  }

  // epilogue: direct write (full-K per wave); C/D: col=lane&15, row=fq*4+r
#pragma unroll
  for (int n2 = 0; n2 < 2; ++n2) {
    int colg = col0 + wn*32 + n2*16 + fm;
    float iv = inv[colg], ad = add[colg];
#pragma unroll
    for (int m2 = 0; m2 < 4; ++m2) {
      int rowg = row0 + wm*64 + m2*16 + fq*4;
#pragma unroll
      for (int r = 0; r < 4; ++r) {
        float v = acc[m2][n2][r]*iv + ad;
        if (RELU) v = fmaxf(v, 0.f);
        Cout[(size_t)(rowg + r)*256 + colg] = v;
      }
    }
  }
}

// ---------------- global average pool (partial sums, atomics) ----------------
__global__ __launch_bounds__(256) void pool_kernel(const float* __restrict__ y2,
                                                   float* __restrict__ pool)
{
  int b = blockIdx.x, t = threadIdx.x;
  int r0 = blockIdx.y * 112;
  float s = 0.f;
  for (int r = 0; r < 112; ++r)
    s += y2[((size_t)b*784 + r0 + r)*256 + t];
  atomicAdd(&pool[b*256 + t], s);
}

// ---------------- SE MLP: scale = sigmoid(relu(mean @ w1 + b1) @ w2 + b2) ----------------
__global__ __launch_bounds__(256) void se_kernel(
    const float* __restrict__ pool, const float* __restrict__ w1, const float* __restrict__ b1,
    const float* __restrict__ w2, const float* __restrict__ b2, float* __restrict__ scale)
{
  __shared__ float m[256];
  __shared__ float hbuf[16];
  int b = blockIdx.x, t = threadIdx.x;
  m[t] = pool[b*256 + t] * (1.f/784.f);
  __syncthreads();
  if (t < 16) {
    float a = b1[t];
    for (int o = 0; o < 256; ++o) a += m[o]*w1[o*16 + t];
    hbuf[t] = fmaxf(a, 0.f);
  }
  __syncthreads();
  float a = b2[t];
#pragma unroll
  for (int jj = 0; jj < 16; ++jj) a += hbuf[jj]*w2[jj*256 + t];
  scale[b*256 + t] = 1.f/(1.f + __expf(-a));
}

// ---------------- final: out = relu(y2 * scale + x), NCHW ----------------
__global__ __launch_bounds__(256) void final_kernel(
    const float* __restrict__ y2, const float* __restrict__ scale,
    const float* __restrict__ x, float* __restrict__ out)
{
  int idx = blockIdx.x*256 + threadIdx.x;
  int b = idx / 200704, rem = idx % 200704;
  int o = rem / 784, hw = rem % 784;
  float v = y2[((size_t)b*784 + hw)*256 + o]*scale[b*256 + o] + x[idx];
  out[idx] = fmaxf(v, 0.f);
}

// ---------------- launch ----------------
extern "C" void kernel_launch(void* const* d_in, const int* in_sizes, int n_in,
                              void* d_out, int out_size, void* d_ws, size_t ws_size,
                              hipStream_t stream) {
  const float* x     = (const float*)d_in[0];
  const float* cent1 = (const float*)d_in[1];
  const float* wsub1 = (const float*)d_in[2];
  const float* g1    = (const float*)d_in[3];
  const float* be1   = (const float*)d_in[4];
  const float* mu1   = (const float*)d_in[5];
  const float* va1   = (const float*)d_in[6];
  const float* cent2 = (const float*)d_in[7];
  const float* wsub2 = (const float*)d_in[8];
  const float* g2    = (const float*)d_in[9];
  const float* be2   = (const float*)d_in[10];
  const float* mu2   = (const float*)d_in[11];
  const float* va2   = (const float*)d_in[12];
  const float* sw1   = (const float*)d_in[13];
  const float* sb1   = (const float*)d_in[14];
  const float* sw2   = (const float*)d_in[15];
  const float* sb2   = (const float*)d_in[16];
  float* out = (float*)d_out;

  char* ws = (char*)d_ws;
  float* centP1 = (float*)(ws + 0);               // 147,456
  float* centP2 = (float*)(ws + 147456);          // 147,456
  float* cnP1   = (float*)(ws + 294912);          // 16,384
  float* cnP2   = (float*)(ws + 311296);          // 16,384
  float* bn1i   = (float*)(ws + 327680);
  float* bn1a   = (float*)(ws + 328704);
  float* bn2i   = (float*)(ws + 329728);
  float* bn2a   = (float*)(ws + 330752);
  float* pool   = (float*)(ws + 331776);          // 16 KB
  float* scale  = (float*)(ws + 348160);          // 16 KB
  f16*   lut1   = (f16*)(ws + 2097152);           // 2 MB (kt-tiled + swizzled)
  f16*   lut2   = (f16*)(ws + 4194304);           // 2 MB
  f16*   attn   = (f16*)(ws + 8388608);           // [64][12544][64] = 102,760,448
  float* y1     = (float*)(ws + 111149056);       // 12,845,056
  float* y2     = (float*)(ws + 123994112);       // 12,845,056 (end ~130.5 MB)

  prep_kernel<<<8225, 256, 0, stream>>>(cent1, wsub1, cent2, wsub2,
                                        g1, be1, mu1, va1, g2, be2, mu2, va2,
                                        lut1, lut2, centP1, centP2, cnP1, cnP2,
                                        bn1i, bn1a, bn2i, bn2a, pool);
  attn_kernel<0><<<dim3(49, 128), 256, 0, stream>>>(x, centP1, cnP1, attn);
  gemm_kernel<true ><<<392, 256, 0, stream>>>(attn, lut1, bn1i, bn1a, y1);
  attn_kernel<1><<<dim3(49, 128), 256, 0, stream>>>(y1, centP2, cnP2, attn);
  gemm_kernel<false><<<392, 256, 0, stream>>>(attn, lut2, bn2i, bn2a, y2);
  pool_kernel<<<dim3(16, 7), 256, 0, stream>>>(y2, pool);
  se_kernel<<<16, 256, 0, stream>>>(pool, sw1, sb1, sw2, sb2, scale);
  final_kernel<<<12544, 256, 0, stream>>>(y2, scale, x, out);
}